// Round 4
// baseline (164.516 us; speedup 1.0000x reference)
//
#include <hip/hip_runtime.h>
#include <hip/hip_bf16.h>

typedef __attribute__((ext_vector_type(8))) short short8;     // 8 bf16 MFMA operand
typedef __attribute__((ext_vector_type(4))) float f32x4;
typedef __attribute__((ext_vector_type(8))) unsigned short ushort8v;

// B=2, T=2048, D_IN=1024, H=16, D_HEAD=64, D_INNER=1024, M=B*T=4096

__device__ __forceinline__ unsigned short f2bf(float f) {
  union { float f; unsigned int u; } x; x.f = f;
  unsigned int r = x.u + 0x7FFFu + ((x.u >> 16) & 1u);   // RNE
  return (unsigned short)(r >> 16);
}

__device__ __forceinline__ unsigned int pk2bf(float lo, float hi) {
  // v_cvt_pk_bf16_f32 via intrinsic (compiler-scheduled; m240: don't hand-asm)
  __hip_bfloat162 b2 = __float22bfloat162_rn(make_float2(lo, hi));
  union { __hip_bfloat162 b; unsigned int u; } c; c.b = b2;
  return c.u;
}

__device__ __forceinline__ void gload_lds16(const void* g, void* l) {
  __builtin_amdgcn_global_load_lds(
      (const __attribute__((address_space(1))) void*)g,
      (__attribute__((address_space(3))) void*)l, 16, 0, 0);
}

// ---------------- fused prep: bias_init + x->bf16 + 4 weight transposes ----------------
// grid: [0,4096) cvt x | [4096,7168) Wq/Wk/Wv transpose | [7168,7232) Wo | [7232,7488) bias

__global__ __launch_bounds__(256) void prep(
    const float* __restrict__ x,
    const float* __restrict__ Wq, const float* __restrict__ Wk, const float* __restrict__ Wv,
    const float* __restrict__ Wo, const float* __restrict__ bo,
    unsigned short* __restrict__ xb,
    unsigned short* __restrict__ wqt, unsigned short* __restrict__ wkt,
    unsigned short* __restrict__ wvt, unsigned short* __restrict__ wot,
    float* __restrict__ out) {
  __shared__ float tile[32][33];
  int b = blockIdx.x;
  if (b < 4096) {                     // x -> bf16, 4 elems/thread
    int i = (b * 256 + threadIdx.x) * 4;
    float4 f = *(const float4*)(x + i);
    ushort4 o;
    o.x = f2bf(f.x); o.y = f2bf(f.y); o.z = f2bf(f.z); o.w = f2bf(f.w);
    *(ushort4*)(xb + i) = o;
  } else if (b < 7168) {              // W^T for Wq/Wk/Wv (1024x1024)
    int idx = b - 4096;
    int z = idx >> 10, rem = idx & 1023;
    const float* src = (z == 0) ? Wq : (z == 1) ? Wk : Wv;
    unsigned short* dst = (z == 0) ? wqt : (z == 1) ? wkt : wvt;
    int kx = (rem & 31) * 32, ny = (rem >> 5) * 32;
    int tx = threadIdx.x & 31, ty = threadIdx.x >> 5;
    #pragma unroll
    for (int r = 0; r < 32; r += 8)
      tile[ty + r][tx] = src[(size_t)(kx + ty + r) * 1024 + ny + tx];
    __syncthreads();
    #pragma unroll
    for (int r = 0; r < 32; r += 8)
      dst[(size_t)(ny + ty + r) * 1024 + kx + tx] = f2bf(tile[tx][ty + r]);
  } else if (b < 7232) {              // Wo^T (1024x64 -> 64x1024)
    int idx = b - 7168;
    int kx = (idx & 31) * 32, ny = (idx >> 5) * 32;
    int tx = threadIdx.x & 31, ty = threadIdx.x >> 5;
    #pragma unroll
    for (int r = 0; r < 32; r += 8)
      tile[ty + r][tx] = Wo[(size_t)(kx + ty + r) * 64 + ny + tx];
    __syncthreads();
    #pragma unroll
    for (int r = 0; r < 32; r += 8)
      wot[(size_t)(ny + ty + r) * 1024 + kx + tx] = f2bf(tile[tx][ty + r]);
  } else {                            // seed out with bias (out is re-poisoned each call)
    int t = (b - 7232) * 256 + threadIdx.x;  // 65536 float4s
    float4 bi = *(const float4*)(bo + (t & 15) * 4);
    *(float4*)(out + (size_t)t * 4) = bi;
  }
}

// ---------------- QKV projection GEMM, BK=64, XOR-swizzled staging ----------------
// z=0/1: A=W^T (m over d_inner), B=x (n over tokens) -> D[d][t]; in-lane r = consecutive d.
// z=2:   A=x (m over tokens), B=Wv^T (n over d_inner) -> D[t][d]; in-lane r = consecutive t.
// Q scale folds BOTH 1/sqrt(1024) AND log2(e): attention softmax runs in exp2 domain.

__global__ __launch_bounds__(256) void qkv_gemm(
    const unsigned short* __restrict__ Xb,
    const unsigned short* __restrict__ Wqt, const unsigned short* __restrict__ Wkt,
    const unsigned short* __restrict__ Wvt,
    unsigned short* __restrict__ Oq, unsigned short* __restrict__ Ok,
    unsigned short* __restrict__ Ovt) {
  constexpr int Kd = 1024;
  __shared__ __align__(16) unsigned short As[128 * 64];
  __shared__ __align__(16) unsigned short Bs[128 * 64];
  int z = blockIdx.z;
  int m0, n0;
  const unsigned short *Arow, *Brow;
  if (z == 2) {          // m tokens (32 tiles), n d_inner (8 tiles)
    m0 = blockIdx.x * 128; n0 = blockIdx.y * 128;
    Arow = Xb; Brow = Wvt;
  } else {               // m d_inner (8 tiles), n tokens (32 tiles)
    m0 = blockIdx.y * 128; n0 = blockIdx.x * 128;
    Arow = (z == 0) ? Wqt : Wkt; Brow = Xb;
  }
  int tid = threadIdx.x, lane = tid & 63, wave = tid >> 6;
  int wm = wave >> 1, wn = wave & 1;
  int l15 = lane & 15, quad = lane >> 4;
  int swz = l15 & 7;

  f32x4 acc[4][4] = {};

  for (int k0 = 0; k0 < Kd; k0 += 64) {
    __syncthreads();
    #pragma unroll
    for (int r = 0; r < 4; ++r) {
      int i = tid + 256 * r;
      int row = i >> 3, c8 = i & 7;
      int gc8 = c8 ^ (row & 7);
      gload_lds16(Arow + (size_t)(m0 + row) * Kd + k0 + gc8 * 8, &As[i * 8]);
    }
    #pragma unroll
    for (int r = 0; r < 4; ++r) {
      int i = tid + 256 * r;
      int row = i >> 3, c8 = i & 7;
      int gc8 = c8 ^ (row & 7);
      gload_lds16(Brow + (size_t)(n0 + row) * Kd + k0 + gc8 * 8, &Bs[i * 8]);
    }
    __syncthreads();
    short8 af[4][2], bf[4][2];
    #pragma unroll
    for (int s = 0; s < 2; ++s) {
      #pragma unroll
      for (int i = 0; i < 4; ++i)
        af[i][s] = *(const short8*)&As[(wm * 64 + i * 16 + l15) * 64 + (((s << 2) + quad) ^ swz) * 8];
      #pragma unroll
      for (int j = 0; j < 4; ++j)
        bf[j][s] = *(const short8*)&Bs[(wn * 64 + j * 16 + l15) * 64 + (((s << 2) + quad) ^ swz) * 8];
    }
    #pragma unroll
    for (int s = 0; s < 2; ++s)
      #pragma unroll
      for (int i = 0; i < 4; ++i)
        #pragma unroll
        for (int j = 0; j < 4; ++j)
          acc[i][j] = __builtin_amdgcn_mfma_f32_16x16x32_bf16(af[i][s], bf[j][s], acc[i][j], 0, 0, 0);
  }

  if (z == 2) {
    // D[t][d] -> Vt[(b*16+h)*64+d][t], pack 4 consecutive t per lane -> b64
    #pragma unroll
    for (int i = 0; i < 4; ++i) {
      int tbase = m0 + wm * 64 + i * 16 + quad * 4;
      int b = tbase >> 11, tt = tbase & 2047;
      #pragma unroll
      for (int j = 0; j < 4; ++j) {
        int dm = n0 + wn * 64 + j * 16 + l15;
        int h = dm >> 6, d = dm & 63;
        unsigned int u0 = f2bf(acc[i][j][0]), u1 = f2bf(acc[i][j][1]);
        unsigned int u2 = f2bf(acc[i][j][2]), u3 = f2bf(acc[i][j][3]);
        uint2 pk; pk.x = u0 | (u1 << 16); pk.y = u2 | (u3 << 16);
        *(uint2*)(Ovt + (((size_t)(b * 16 + h) * 64 + d) << 11) + tt) = pk;
      }
    }
  } else {
    // D[d][t] -> O[(b*16+h)*2048+t][d], pack 4 consecutive d per lane -> b64
    unsigned short* O = (z == 0) ? Oq : Ok;
    // 1/sqrt(1024) * log2(e) folded into Q so attention uses exp2 directly
    float scale = (z == 0) ? 0.0450842200f : 1.0f;
    #pragma unroll
    for (int i = 0; i < 4; ++i) {
      int dmbase = m0 + wm * 64 + i * 16 + quad * 4;
      int h = dmbase >> 6, d0 = dmbase & 63;
      #pragma unroll
      for (int j = 0; j < 4; ++j) {
        int t = n0 + wn * 64 + j * 16 + l15;
        int b = t >> 11, tt = t & 2047;
        unsigned int u0 = f2bf(acc[i][j][0] * scale), u1 = f2bf(acc[i][j][1] * scale);
        unsigned int u2 = f2bf(acc[i][j][2] * scale), u3 = f2bf(acc[i][j][3] * scale);
        uint2 pk; pk.x = u0 | (u1 << 16); pk.y = u2 | (u3 << 16);
        *(uint2*)(O + (((size_t)(b * 16 + h) * 2048 + tt) << 6) + d0) = pk;
      }
    }
  }
}

// ---------------- fused causal flash attention v12: pipelined softmax ----------------
// vs v11: the per-wave serial chain QK->softmax->PV->barrier leaves both pipes
// idle half the time (MfmaUtil 14%, VALUBusy 38%, ~50% no-issue). Pipeline it:
// in iteration kt, QK(kt+1) (MFMA stream, reads the OTHER dbuf half staged last
// iter) is emitted alongside softmax(kt) (VALU stream) -- independent, so the
// scheduler interleaves them; then PV(kt). Stage-writes of tile kt+2 go into
// the CURRENT buffer (V(kt) was read this iter), so they are fenced by barriers
// on both sides: 2 barriers/iter, but ~300 cyc/iter of MFMA/VALU overlap won.
// P-pack now via v_cvt_pk_bf16_f32 intrinsic (-~24 VALU instr/iter).
// Keeps: XOR-swizzled LDS, exp2 softmax, defer-max, setprio on PV, 1024-block
// grid with the balanced quadruple map.

__global__ __launch_bounds__(256, 4) void attn12(
    const unsigned short* __restrict__ Qg, const unsigned short* __restrict__ Kg,
    const unsigned short* __restrict__ Vtg, unsigned short* __restrict__ Yg) {
  constexpr int T = 2048;
  __shared__ __align__(16) unsigned short Ks[2][64 * 64];   // [tok][d], XOR-swz
  __shared__ __align__(16) unsigned short Vs[2][64 * 64];   // [d][tok], XOR-swz
  __shared__ __align__(16) unsigned short Ps[4][16 * 64];   // per-wave, XOR-swz
  int bh = blockIdx.x;
  int by = blockIdx.y;
  int g = by >> 3, w8 = by & 7;
  int qt = (g == 0) ? w8 : (g == 1) ? (15 - w8) : (g == 2) ? (16 + w8) : (31 - w8);
  int tid = threadIdx.x, lane = tid & 63, wave = tid >> 6;
  int l15 = lane & 15, quad = lane >> 4;
  int swz = l15 & 7;
  const unsigned short* Qb = Qg + (size_t)bh * T * 64;
  const unsigned short* Kb = Kg + (size_t)bh * T * 64;
  const unsigned short* Vb = Vtg + (size_t)bh * 64 * T;
  int h = bh & 15, b = bh >> 4;
  int qw = qt * 64 + wave * 16;

  // Q as B-operand frags (regs): lane n=q(l15), k=d(quad*8+32s)
  short8 qf[2];
  #pragma unroll
  for (int s = 0; s < 2; ++s)
    qf[s] = *(const short8*)(Qb + (size_t)(qw + l15) * 64 + quad * 8 + 32 * s);

  f32x4 Oacc[4] = {};
  float m_run = -__builtin_inff();
  float l_run = 0.f;

  // staging: thread stages rows srow and srow+32; swizzled granule within row.
  int srow = tid >> 3, sc8 = tid & 7;
  int sdst = srow * 64 + ((sc8 ^ (srow & 7)) * 8);

  // ---- prologue: stage tiles 0 and 1 (tile 1 always in-bounds; unused if qt==0)
  {
    ushort8v kA[2], vA[2], kB[2], vB[2];
    #pragma unroll
    for (int r = 0; r < 2; ++r) {
      kA[r] = *(const ushort8v*)(Kb + (size_t)(srow + 32 * r) * 64 + sc8 * 8);
      vA[r] = *(const ushort8v*)(Vb + (size_t)(srow + 32 * r) * T + sc8 * 8);
      kB[r] = *(const ushort8v*)(Kb + (size_t)(64 + srow + 32 * r) * 64 + sc8 * 8);
      vB[r] = *(const ushort8v*)(Vb + (size_t)(srow + 32 * r) * T + 64 + sc8 * 8);
    }
    *(ushort8v*)&Ks[0][sdst] = kA[0];
    *(ushort8v*)&Ks[0][sdst + 2048] = kA[1];
    *(ushort8v*)&Vs[0][sdst] = vA[0];
    *(ushort8v*)&Vs[0][sdst + 2048] = vA[1];
    *(ushort8v*)&Ks[1][sdst] = kB[0];
    *(ushort8v*)&Ks[1][sdst + 2048] = kB[1];
    *(ushort8v*)&Vs[1][sdst] = vB[0];
    *(ushort8v*)&Vs[1][sdst + 2048] = vB[1];
  }
  __syncthreads();

  // S = QK(0)
  f32x4 S[4] = {};
  #pragma unroll
  for (int s = 0; s < 2; ++s)
    #pragma unroll
    for (int mi = 0; mi < 4; ++mi) {
      short8 kf = *(const short8*)&Ks[0][(mi * 16 + l15) * 64 + ((quad + 4 * s) ^ swz) * 8];
      S[mi] = __builtin_amdgcn_mfma_f32_16x16x32_bf16(kf, qf[s], S[mi], 0, 0, 0);
    }

  ushort8v kpre[2], vpre[2];
  for (int kt = 0; kt <= qt; ++kt) {
    int cur = kt & 1;
    bool haveNext = (kt + 1 <= qt);
    bool haveNext2 = (kt + 2 <= qt);

    // A: issue global loads for tile kt+2 (consumed at E this iter)
    if (haveNext2) {
      #pragma unroll
      for (int r = 0; r < 2; ++r) {
        kpre[r] = *(const ushort8v*)(Kb + (size_t)((kt + 2) * 64 + srow + 32 * r) * 64 + sc8 * 8);
        vpre[r] = *(const ushort8v*)(Vb + (size_t)(srow + 32 * r) * T + (kt + 2) * 64 + sc8 * 8);
      }
    }

    // C: Sn = QK(kt+1) from the other buffer — independent of softmax(kt),
    // interleaves with it (MFMA pipe || VALU pipe).
    f32x4 Sn[4] = {};
    if (haveNext) {
      #pragma unroll
      for (int s = 0; s < 2; ++s)
        #pragma unroll
        for (int mi = 0; mi < 4; ++mi) {
          short8 kf = *(const short8*)&Ks[cur ^ 1][(mi * 16 + l15) * 64 + ((quad + 4 * s) ^ swz) * 8];
          Sn[mi] = __builtin_amdgcn_mfma_f32_16x16x32_bf16(kf, qf[s], Sn[mi], 0, 0, 0);
        }
    }

    // B: softmax(kt)
    if (kt == qt) {  // diagonal tile: causal mask
      int ql = wave * 16 + l15;
      #pragma unroll
      for (int mi = 0; mi < 4; ++mi) {
        int tokl = mi * 16 + quad * 4;
        #pragma unroll
        for (int r = 0; r < 4; ++r)
          if (tokl + r > ql) S[mi][r] = -__builtin_inff();
      }
    }

    float t0 = fmaxf(fmaxf(S[0][0], S[0][1]), fmaxf(S[0][2], S[0][3]));
    float t1 = fmaxf(fmaxf(S[1][0], S[1][1]), fmaxf(S[1][2], S[1][3]));
    float t2 = fmaxf(fmaxf(S[2][0], S[2][1]), fmaxf(S[2][2], S[2][3]));
    float t3 = fmaxf(fmaxf(S[3][0], S[3][1]), fmaxf(S[3][2], S[3][3]));
    float vmax = fmaxf(fmaxf(t0, t1), fmaxf(t2, t3));
    vmax = fmaxf(vmax, __shfl_xor(vmax, 16));
    vmax = fmaxf(vmax, __shfl_xor(vmax, 32));
    float mold = m_run;
    bool defer = __all(vmax - mold <= 8.f) != 0;   // mold=-inf -> false
    float mnew = defer ? mold : fmaxf(mold, vmax);
    float alpha = defer ? 1.f : __builtin_amdgcn_exp2f(mold - mnew);
    m_run = mnew;
    float rs = 0.f;
    #pragma unroll
    for (int mi = 0; mi < 4; ++mi) {
      float p0 = __builtin_amdgcn_exp2f(S[mi][0] - mnew);
      float p1 = __builtin_amdgcn_exp2f(S[mi][1] - mnew);
      float p2 = __builtin_amdgcn_exp2f(S[mi][2] - mnew);
      float p3 = __builtin_amdgcn_exp2f(S[mi][3] - mnew);
      rs += (p0 + p1) + (p2 + p3);
      uint2 pk;
      pk.x = pk2bf(p0, p1);
      pk.y = pk2bf(p2, p3);
      int gg = (2 * mi + (quad >> 1)) ^ swz;
      *(uint2*)&Ps[wave][l15 * 64 + gg * 8 + (quad & 1) * 4] = pk;
    }
    rs += __shfl_xor(rs, 16);
    rs += __shfl_xor(rs, 32);
    l_run = l_run * alpha + rs;

    if (!defer)
      #pragma unroll
      for (int jd = 0; jd < 4; ++jd)
        #pragma unroll
        for (int r = 0; r < 4; ++r)
          Oacc[jd][r] *= alpha;

    // D: PV(kt) from Vs[cur] + Ps
    __builtin_amdgcn_s_setprio(1);
    #pragma unroll
    for (int s = 0; s < 2; ++s) {
      short8 pf = *(const short8*)&Ps[wave][l15 * 64 + ((quad + 4 * s) ^ swz) * 8];
      #pragma unroll
      for (int jd = 0; jd < 4; ++jd) {
        short8 vfr = *(const short8*)&Vs[cur][(jd * 16 + l15) * 64 + ((quad + 4 * s) ^ swz) * 8];
        Oacc[jd] = __builtin_amdgcn_mfma_f32_16x16x32_bf16(vfr, pf, Oacc[jd], 0, 0, 0);
      }
    }
    __builtin_amdgcn_s_setprio(0);

    // E: stage tile kt+2 into buf cur (overwrites K/V(kt)); fenced both sides.
    if (haveNext2) {
      __syncthreads();   // all waves done with PV(kt) reads of Vs[cur]
      *(ushort8v*)&Ks[cur][sdst] = kpre[0];
      *(ushort8v*)&Ks[cur][sdst + 2048] = kpre[1];
      *(ushort8v*)&Vs[cur][sdst] = vpre[0];
      *(ushort8v*)&Vs[cur][sdst + 2048] = vpre[1];
      __syncthreads();   // writes visible before next iter's QK(kt+2) reads
    }

    // rotate S <- Sn
    if (haveNext) {
      #pragma unroll
      for (int mi = 0; mi < 4; ++mi) S[mi] = Sn[mi];
    }
  }

  // finalize: O^T/l per-lane; Y write b64 per jd
  {
    float linv = 1.f / l_run;
    int q = qw + l15;
    size_t row = (size_t)(b * 2048 + q) * 1024 + h * 64 + quad * 4;
    #pragma unroll
    for (int jd = 0; jd < 4; ++jd) {
      unsigned int u0 = f2bf(Oacc[jd][0] * linv), u1 = f2bf(Oacc[jd][1] * linv);
      unsigned int u2 = f2bf(Oacc[jd][2] * linv), u3 = f2bf(Oacc[jd][3] * linv);
      uint2 pk; pk.x = u0 | (u1 << 16); pk.y = u2 | (u3 << 16);
      *(uint2*)(Yg + row + jd * 16) = pk;
    }
  }
}

// ---------------- out projection: split-K atomics onto bias-seeded out ----------------

__global__ __launch_bounds__(256) void oproj(
    const unsigned short* __restrict__ Y, const unsigned short* __restrict__ Wot,
    float* __restrict__ out) {
  __shared__ __align__(16) unsigned short As[64 * 32];
  __shared__ __align__(16) unsigned short Bs[64 * 32];
  int m0 = blockIdx.x * 64;
  int kbase = blockIdx.y * 256;  // 4-way split-K
  int tid = threadIdx.x, lane = tid & 63, wave = tid >> 6;
  int l15 = lane & 15, quad = lane >> 4;
  f32x4 acc[4] = {};
  for (int k0 = kbase; k0 < kbase + 256; k0 += 32) {
    __syncthreads();
    {
      int row = tid >> 2, c8 = (tid & 3) * 8;
      gload_lds16(Y + (size_t)(m0 + row) * 1024 + k0 + c8, &As[tid * 8]);
      gload_lds16(Wot + (size_t)row * 1024 + k0 + c8, &Bs[tid * 8]);
    }
    __syncthreads();
    short8 af = *(const short8*)&As[(wave * 16 + l15) * 32 + quad * 8];
    #pragma unroll
    for (int j = 0; j < 4; ++j) {
      short8 bf = *(const short8*)&Bs[(j * 16 + l15) * 32 + quad * 8];
      acc[j] = __builtin_amdgcn_mfma_f32_16x16x32_bf16(af, bf, acc[j], 0, 0, 0);
    }
  }
  #pragma unroll
  for (int j = 0; j < 4; ++j) {
    int n = j * 16 + l15;
    #pragma unroll
    for (int r = 0; r < 4; ++r) {
      int m = m0 + wave * 16 + quad * 4 + r;
      atomicAdd(&out[(size_t)m * 64 + n], acc[j][r]);
    }
  }
}

// ---------------- launcher (4 kernels total) ----------------

extern "C" void kernel_launch(void* const* d_in, const int* in_sizes, int n_in,
                              void* d_out, int out_size, void* d_ws, size_t ws_size,
                              hipStream_t stream) {
  const float* x  = (const float*)d_in[0];
  const float* Wq = (const float*)d_in[1];
  const float* Wk = (const float*)d_in[2];
  const float* Wv = (const float*)d_in[3];
  const float* Wo = (const float*)d_in[4];
  const float* bo = (const float*)d_in[5];
  float* out = (float*)d_out;
  char* ws = (char*)d_ws;

  unsigned short* xb  = (unsigned short*)(ws);                       // 8 MB  [4096][1024]
  unsigned short* wqt = (unsigned short*)(ws + (8ull << 20));        // 2 MB  Wq^T
  unsigned short* wkt = (unsigned short*)(ws + (10ull << 20));       // 2 MB
  unsigned short* wvt = (unsigned short*)(ws + (12ull << 20));       // 2 MB
  unsigned short* wot = (unsigned short*)(ws + (14ull << 20));       // 128 KB Wo^T
  unsigned short* q   = (unsigned short*)(ws + (15ull << 20));       // 8 MB  [b][h][t][d]
  unsigned short* k   = (unsigned short*)(ws + (23ull << 20));       // 8 MB  [b][h][t][d]
  unsigned short* vt  = (unsigned short*)(ws + (31ull << 20));       // 8 MB  [b][h][d][t]
  unsigned short* y   = (unsigned short*)(ws + (39ull << 20));       // 8 MB  [4096][1024]

  prep<<<7488, 256, 0, stream>>>(x, Wq, Wk, Wv, Wo, bo, xb, wqt, wkt, wvt, wot, out);
  qkv_gemm<<<dim3(32, 8, 3), 256, 0, stream>>>(xb, wqt, wkt, wvt, q, k, vt);
  attn12<<<dim3(32, 32), 256, 0, stream>>>(q, k, vt, y);
  oproj<<<dim3(64, 4), 256, 0, stream>>>(y, wot, out);
}

// Round 5
// 153.665 us; speedup vs baseline: 1.0706x; 1.0706x over previous
//
#include <hip/hip_runtime.h>
#include <hip/hip_bf16.h>

typedef __attribute__((ext_vector_type(8))) short short8;     // 8 bf16 MFMA operand
typedef __attribute__((ext_vector_type(4))) float f32x4;
typedef __attribute__((ext_vector_type(8))) unsigned short ushort8v;

// B=2, T=2048, D_IN=1024, H=16, D_HEAD=64, D_INNER=1024, M=B*T=4096

__device__ __forceinline__ unsigned short f2bf(float f) {
  union { float f; unsigned int u; } x; x.f = f;
  unsigned int r = x.u + 0x7FFFu + ((x.u >> 16) & 1u);   // RNE
  return (unsigned short)(r >> 16);
}

__device__ __forceinline__ unsigned int pk2bf(float lo, float hi) {
  __hip_bfloat162 b2 = __float22bfloat162_rn(make_float2(lo, hi));
  union { __hip_bfloat162 b; unsigned int u; } c; c.b = b2;
  return c.u;
}

__device__ __forceinline__ void gload_lds16(const void* g, void* l) {
  __builtin_amdgcn_global_load_lds(
      (const __attribute__((address_space(1))) void*)g,
      (__attribute__((address_space(3))) void*)l, 16, 0, 0);
}

// ---------------- fused prep: bias_init + x->bf16 + 4 weight transposes ----------------
// grid: [0,4096) cvt x | [4096,7168) Wq/Wk/Wv transpose | [7168,7232) Wo | [7232,7488) bias

__global__ __launch_bounds__(256) void prep(
    const float* __restrict__ x,
    const float* __restrict__ Wq, const float* __restrict__ Wk, const float* __restrict__ Wv,
    const float* __restrict__ Wo, const float* __restrict__ bo,
    unsigned short* __restrict__ xb,
    unsigned short* __restrict__ wqt, unsigned short* __restrict__ wkt,
    unsigned short* __restrict__ wvt, unsigned short* __restrict__ wot,
    float* __restrict__ out) {
  __shared__ float tile[32][33];
  int b = blockIdx.x;
  if (b < 4096) {                     // x -> bf16, 4 elems/thread
    int i = (b * 256 + threadIdx.x) * 4;
    float4 f = *(const float4*)(x + i);
    ushort4 o;
    o.x = f2bf(f.x); o.y = f2bf(f.y); o.z = f2bf(f.z); o.w = f2bf(f.w);
    *(ushort4*)(xb + i) = o;
  } else if (b < 7168) {              // W^T for Wq/Wk/Wv (1024x1024)
    int idx = b - 4096;
    int z = idx >> 10, rem = idx & 1023;
    const float* src = (z == 0) ? Wq : (z == 1) ? Wk : Wv;
    unsigned short* dst = (z == 0) ? wqt : (z == 1) ? wkt : wvt;
    int kx = (rem & 31) * 32, ny = (rem >> 5) * 32;
    int tx = threadIdx.x & 31, ty = threadIdx.x >> 5;
    #pragma unroll
    for (int r = 0; r < 32; r += 8)
      tile[ty + r][tx] = src[(size_t)(kx + ty + r) * 1024 + ny + tx];
    __syncthreads();
    #pragma unroll
    for (int r = 0; r < 32; r += 8)
      dst[(size_t)(ny + ty + r) * 1024 + kx + tx] = f2bf(tile[tx][ty + r]);
  } else if (b < 7232) {              // Wo^T (1024x64 -> 64x1024)
    int idx = b - 7168;
    int kx = (idx & 31) * 32, ny = (idx >> 5) * 32;
    int tx = threadIdx.x & 31, ty = threadIdx.x >> 5;
    #pragma unroll
    for (int r = 0; r < 32; r += 8)
      tile[ty + r][tx] = Wo[(size_t)(kx + ty + r) * 64 + ny + tx];
    __syncthreads();
    #pragma unroll
    for (int r = 0; r < 32; r += 8)
      wot[(size_t)(ny + ty + r) * 1024 + kx + tx] = f2bf(tile[tx][ty + r]);
  } else {                            // seed out with bias (out is re-poisoned each call)
    int t = (b - 7232) * 256 + threadIdx.x;  // 65536 float4s
    float4 bi = *(const float4*)(bo + (t & 15) * 4);
    *(float4*)(out + (size_t)t * 4) = bi;
  }
}

// ---------------- QKV projection GEMM, BK=64, XOR-swizzled staging ----------------
// z=0/1: A=W^T (m over d_inner), B=x (n over tokens) -> D[d][t]; in-lane r = consecutive d.
// z=2:   A=x (m over tokens), B=Wv^T (n over d_inner) -> D[t][d]; in-lane r = consecutive t.
// Q scale folds BOTH 1/sqrt(1024) AND log2(e): attention softmax runs in exp2 domain.

__global__ __launch_bounds__(256) void qkv_gemm(
    const unsigned short* __restrict__ Xb,
    const unsigned short* __restrict__ Wqt, const unsigned short* __restrict__ Wkt,
    const unsigned short* __restrict__ Wvt,
    unsigned short* __restrict__ Oq, unsigned short* __restrict__ Ok,
    unsigned short* __restrict__ Ovt) {
  constexpr int Kd = 1024;
  __shared__ __align__(16) unsigned short As[128 * 64];
  __shared__ __align__(16) unsigned short Bs[128 * 64];
  int z = blockIdx.z;
  int m0, n0;
  const unsigned short *Arow, *Brow;
  if (z == 2) {          // m tokens (32 tiles), n d_inner (8 tiles)
    m0 = blockIdx.x * 128; n0 = blockIdx.y * 128;
    Arow = Xb; Brow = Wvt;
  } else {               // m d_inner (8 tiles), n tokens (32 tiles)
    m0 = blockIdx.y * 128; n0 = blockIdx.x * 128;
    Arow = (z == 0) ? Wqt : Wkt; Brow = Xb;
  }
  int tid = threadIdx.x, lane = tid & 63, wave = tid >> 6;
  int wm = wave >> 1, wn = wave & 1;
  int l15 = lane & 15, quad = lane >> 4;
  int swz = l15 & 7;

  f32x4 acc[4][4] = {};

  for (int k0 = 0; k0 < Kd; k0 += 64) {
    __syncthreads();
    #pragma unroll
    for (int r = 0; r < 4; ++r) {
      int i = tid + 256 * r;
      int row = i >> 3, c8 = i & 7;
      int gc8 = c8 ^ (row & 7);
      gload_lds16(Arow + (size_t)(m0 + row) * Kd + k0 + gc8 * 8, &As[i * 8]);
    }
    #pragma unroll
    for (int r = 0; r < 4; ++r) {
      int i = tid + 256 * r;
      int row = i >> 3, c8 = i & 7;
      int gc8 = c8 ^ (row & 7);
      gload_lds16(Brow + (size_t)(n0 + row) * Kd + k0 + gc8 * 8, &Bs[i * 8]);
    }
    __syncthreads();
    short8 af[4][2], bf[4][2];
    #pragma unroll
    for (int s = 0; s < 2; ++s) {
      #pragma unroll
      for (int i = 0; i < 4; ++i)
        af[i][s] = *(const short8*)&As[(wm * 64 + i * 16 + l15) * 64 + (((s << 2) + quad) ^ swz) * 8];
      #pragma unroll
      for (int j = 0; j < 4; ++j)
        bf[j][s] = *(const short8*)&Bs[(wn * 64 + j * 16 + l15) * 64 + (((s << 2) + quad) ^ swz) * 8];
    }
    #pragma unroll
    for (int s = 0; s < 2; ++s)
      #pragma unroll
      for (int i = 0; i < 4; ++i)
        #pragma unroll
        for (int j = 0; j < 4; ++j)
          acc[i][j] = __builtin_amdgcn_mfma_f32_16x16x32_bf16(af[i][s], bf[j][s], acc[i][j], 0, 0, 0);
  }

  if (z == 2) {
    // D[t][d] -> Vt[(b*16+h)*64+d][t], pack 4 consecutive t per lane -> b64
    #pragma unroll
    for (int i = 0; i < 4; ++i) {
      int tbase = m0 + wm * 64 + i * 16 + quad * 4;
      int b = tbase >> 11, tt = tbase & 2047;
      #pragma unroll
      for (int j = 0; j < 4; ++j) {
        int dm = n0 + wn * 64 + j * 16 + l15;
        int h = dm >> 6, d = dm & 63;
        unsigned int u0 = f2bf(acc[i][j][0]), u1 = f2bf(acc[i][j][1]);
        unsigned int u2 = f2bf(acc[i][j][2]), u3 = f2bf(acc[i][j][3]);
        uint2 pk; pk.x = u0 | (u1 << 16); pk.y = u2 | (u3 << 16);
        *(uint2*)(Ovt + (((size_t)(b * 16 + h) * 64 + d) << 11) + tt) = pk;
      }
    }
  } else {
    // D[d][t] -> O[(b*16+h)*2048+t][d], pack 4 consecutive d per lane -> b64
    unsigned short* O = (z == 0) ? Oq : Ok;
    // 1/sqrt(1024) * log2(e) folded into Q so attention uses exp2 directly
    float scale = (z == 0) ? 0.0450842200f : 1.0f;
    #pragma unroll
    for (int i = 0; i < 4; ++i) {
      int dmbase = m0 + wm * 64 + i * 16 + quad * 4;
      int h = dmbase >> 6, d0 = dmbase & 63;
      #pragma unroll
      for (int j = 0; j < 4; ++j) {
        int t = n0 + wn * 64 + j * 16 + l15;
        int b = t >> 11, tt = t & 2047;
        unsigned int u0 = f2bf(acc[i][j][0] * scale), u1 = f2bf(acc[i][j][1] * scale);
        unsigned int u2 = f2bf(acc[i][j][2] * scale), u3 = f2bf(acc[i][j][3] * scale);
        uint2 pk; pk.x = u0 | (u1 << 16); pk.y = u2 | (u3 << 16);
        *(uint2*)(O + (((size_t)(b * 16 + h) * 2048 + tt) << 6) + d0) = pk;
      }
    }
  }
}

// ---------------- fused causal flash attention v13 = v11 loop + fused out-proj ----------------
// Main loop EXACTLY v11 (best measured 46.1us; v12's pipelined softmax regressed -> reverted).
// NEW epilogue: out-projection fused per (b,h,q-tile) block. Normalize Oacc -> bf16
// into this wave's OWN Ps slot (2KB, granule-XOR swizzle, zero barriers), load 8
// Wo^T B-frags (L2-hot), 8 MFMAs, 16 f32 atomicAdds/lane onto bias-seeded out.
// Deletes oproj kernel + 8MB Y write + 8MB Y read + one launch/drain gap.

__global__ __launch_bounds__(256, 4) void attn13(
    const unsigned short* __restrict__ Qg, const unsigned short* __restrict__ Kg,
    const unsigned short* __restrict__ Vtg, const unsigned short* __restrict__ Wot,
    float* __restrict__ out) {
  constexpr int T = 2048;
  __shared__ __align__(16) unsigned short Ks[2][64 * 64];   // [tok][d], XOR-swz
  __shared__ __align__(16) unsigned short Vs[2][64 * 64];   // [d][tok], XOR-swz
  __shared__ __align__(16) unsigned short Ps[4][16 * 64];   // per-wave, XOR-swz (reused as Y tile in epilogue)
  int bh = blockIdx.x;
  int by = blockIdx.y;
  int g = by >> 3, w8 = by & 7;
  int qt = (g == 0) ? w8 : (g == 1) ? (15 - w8) : (g == 2) ? (16 + w8) : (31 - w8);
  int tid = threadIdx.x, lane = tid & 63, wave = tid >> 6;
  int l15 = lane & 15, quad = lane >> 4;
  int swz = l15 & 7;
  const unsigned short* Qb = Qg + (size_t)bh * T * 64;
  const unsigned short* Kb = Kg + (size_t)bh * T * 64;
  const unsigned short* Vb = Vtg + (size_t)bh * 64 * T;
  int h = bh & 15, b = bh >> 4;
  int qw = qt * 64 + wave * 16;

  // Q as B-operand frags (regs): lane n=q(l15), k=d(quad*8+32s)
  short8 qf[2];
  #pragma unroll
  for (int s = 0; s < 2; ++s)
    qf[s] = *(const short8*)(Qb + (size_t)(qw + l15) * 64 + quad * 8 + 32 * s);

  f32x4 Oacc[4] = {};
  float m_run = -__builtin_inff();
  float l_run = 0.f;

  // staging: thread stages rows srow and srow+32; swizzled granule within row.
  int srow = tid >> 3, sc8 = tid & 7;
  int sdst = srow * 64 + ((sc8 ^ (srow & 7)) * 8);

  ushort8v kpre[2], vpre[2];
  #pragma unroll
  for (int r = 0; r < 2; ++r) {
    kpre[r] = *(const ushort8v*)(Kb + (size_t)(srow + 32 * r) * 64 + sc8 * 8);
    vpre[r] = *(const ushort8v*)(Vb + (size_t)(srow + 32 * r) * T + sc8 * 8);
  }
  *(ushort8v*)&Ks[0][sdst] = kpre[0];
  *(ushort8v*)&Ks[0][sdst + 2048] = kpre[1];
  *(ushort8v*)&Vs[0][sdst] = vpre[0];
  *(ushort8v*)&Vs[0][sdst + 2048] = vpre[1];
  __syncthreads();

  for (int kt = 0; kt <= qt; ++kt) {
    const unsigned short* Kl = Ks[kt & 1];
    const unsigned short* Vl = Vs[kt & 1];
    unsigned short* Kn = Ks[(kt & 1) ^ 1];
    unsigned short* Vn = Vs[(kt & 1) ^ 1];

    // issue next-tile loads early (HBM/L2 latency hides under QK^T + softmax)
    if (kt < qt) {
      #pragma unroll
      for (int r = 0; r < 2; ++r) {
        kpre[r] = *(const ushort8v*)(Kb + (size_t)((kt + 1) * 64 + srow + 32 * r) * 64 + sc8 * 8);
        vpre[r] = *(const ushort8v*)(Vb + (size_t)(srow + 32 * r) * T + (kt + 1) * 64 + sc8 * 8);
      }
    }

    f32x4 S[4] = {};
    __builtin_amdgcn_s_setprio(1);
    #pragma unroll
    for (int s = 0; s < 2; ++s)
      #pragma unroll
      for (int mi = 0; mi < 4; ++mi) {
        short8 kf = *(const short8*)&Kl[(mi * 16 + l15) * 64 + ((quad + 4 * s) ^ swz) * 8];
        S[mi] = __builtin_amdgcn_mfma_f32_16x16x32_bf16(kf, qf[s], S[mi], 0, 0, 0);
      }
    __builtin_amdgcn_s_setprio(0);

    if (kt == qt) {  // diagonal tile: causal mask
      int ql = wave * 16 + l15;
      #pragma unroll
      for (int mi = 0; mi < 4; ++mi) {
        int tokl = mi * 16 + quad * 4;
        #pragma unroll
        for (int r = 0; r < 4; ++r)
          if (tokl + r > ql) S[mi][r] = -__builtin_inff();
      }
    }

    float t0 = fmaxf(fmaxf(S[0][0], S[0][1]), fmaxf(S[0][2], S[0][3]));
    float t1 = fmaxf(fmaxf(S[1][0], S[1][1]), fmaxf(S[1][2], S[1][3]));
    float t2 = fmaxf(fmaxf(S[2][0], S[2][1]), fmaxf(S[2][2], S[2][3]));
    float t3 = fmaxf(fmaxf(S[3][0], S[3][1]), fmaxf(S[3][2], S[3][3]));
    float vmax = fmaxf(fmaxf(t0, t1), fmaxf(t2, t3));
    vmax = fmaxf(vmax, __shfl_xor(vmax, 16));
    vmax = fmaxf(vmax, __shfl_xor(vmax, 32));
    float mold = m_run;
    bool defer = __all(vmax - mold <= 8.f) != 0;   // mold=-inf -> false
    float mnew = defer ? mold : fmaxf(mold, vmax);
    float alpha = defer ? 1.f : __builtin_amdgcn_exp2f(mold - mnew);
    m_run = mnew;
    float rs = 0.f;
    #pragma unroll
    for (int mi = 0; mi < 4; ++mi) {
      float p0 = __builtin_amdgcn_exp2f(S[mi][0] - mnew);
      float p1 = __builtin_amdgcn_exp2f(S[mi][1] - mnew);
      float p2 = __builtin_amdgcn_exp2f(S[mi][2] - mnew);
      float p3 = __builtin_amdgcn_exp2f(S[mi][3] - mnew);
      rs += (p0 + p1) + (p2 + p3);
      uint2 pk;
      pk.x = pk2bf(p0, p1);
      pk.y = pk2bf(p2, p3);
      int gg = (2 * mi + (quad >> 1)) ^ swz;
      *(uint2*)&Ps[wave][l15 * 64 + gg * 8 + (quad & 1) * 4] = pk;
    }
    rs += __shfl_xor(rs, 16);
    rs += __shfl_xor(rs, 32);
    l_run = l_run * alpha + rs;

    if (!defer)
      #pragma unroll
      for (int jd = 0; jd < 4; ++jd)
        #pragma unroll
        for (int r = 0; r < 4; ++r)
          Oacc[jd][r] *= alpha;

    // write-late: stage tile kt+1 into the other buffer
    if (kt < qt) {
      *(ushort8v*)&Kn[sdst] = kpre[0];
      *(ushort8v*)&Kn[sdst + 2048] = kpre[1];
      *(ushort8v*)&Vn[sdst] = vpre[0];
      *(ushort8v*)&Vn[sdst + 2048] = vpre[1];
    }

    __builtin_amdgcn_s_setprio(1);
    #pragma unroll
    for (int s = 0; s < 2; ++s) {
      short8 pf = *(const short8*)&Ps[wave][l15 * 64 + ((quad + 4 * s) ^ swz) * 8];
      #pragma unroll
      for (int jd = 0; jd < 4; ++jd) {
        short8 vfr = *(const short8*)&Vl[(jd * 16 + l15) * 64 + ((quad + 4 * s) ^ swz) * 8];
        Oacc[jd] = __builtin_amdgcn_mfma_f32_16x16x32_bf16(vfr, pf, Oacc[jd], 0, 0, 0);
      }
    }
    __builtin_amdgcn_s_setprio(0);
    if (kt < qt) __syncthreads();
  }

  // ---- fused out-projection epilogue (no barriers: each wave uses only its own Ps slot) ----
  {
    float linv = 1.f / l_run;
    unsigned short* Yl = &Ps[wave][0];   // 2KB: row q=wave*16+l15 lives at l15*64 within slot
    #pragma unroll
    for (int jd = 0; jd < 4; ++jd) {
      uint2 pk;
      pk.x = pk2bf(Oacc[jd][0] * linv, Oacc[jd][1] * linv);
      pk.y = pk2bf(Oacc[jd][2] * linv, Oacc[jd][3] * linv);
      // Y[q=l15][d = jd*16 + quad*4 + 0..3]; granule = jd*2 + (quad>>1), XOR row swizzle
      int gg = (jd * 2 + (quad >> 1)) ^ swz;
      *(uint2*)&Yl[l15 * 64 + gg * 8 + (quad & 1) * 4] = pk;
    }
    // Wo^T B-frags: col n=l15 (dout), k=dh h*64+quad*8+32s (L2-hot, 4KB/head)
    short8 wof[4][2];
    #pragma unroll
    for (int nt = 0; nt < 4; ++nt)
      #pragma unroll
      for (int s = 0; s < 2; ++s)
        wof[nt][s] = *(const short8*)(Wot + (size_t)(nt * 16 + l15) * 1024 + h * 64 + quad * 8 + 32 * s);
    // A-frags: row q=l15, k=dh quad*8+32s (same-wave LDS roundtrip; lgkmcnt orders)
    f32x4 acc2[4] = {};
    #pragma unroll
    for (int s = 0; s < 2; ++s) {
      short8 ya = *(const short8*)&Yl[l15 * 64 + (((quad + 4 * s) ^ swz) * 8)];
      #pragma unroll
      for (int nt = 0; nt < 4; ++nt)
        acc2[nt] = __builtin_amdgcn_mfma_f32_16x16x32_bf16(ya, wof[nt][s], acc2[nt], 0, 0, 0);
    }
    // out[token][dout] += head-h contribution (out pre-seeded with bias by prep)
    int q0 = b * 2048 + qt * 64 + wave * 16 + quad * 4;
    #pragma unroll
    for (int nt = 0; nt < 4; ++nt)
      #pragma unroll
      for (int r = 0; r < 4; ++r)
        atomicAdd(&out[(size_t)(q0 + r) * 64 + nt * 16 + l15], acc2[nt][r]);
  }
}

// ---------------- launcher (3 kernels total) ----------------

extern "C" void kernel_launch(void* const* d_in, const int* in_sizes, int n_in,
                              void* d_out, int out_size, void* d_ws, size_t ws_size,
                              hipStream_t stream) {
  const float* x  = (const float*)d_in[0];
  const float* Wq = (const float*)d_in[1];
  const float* Wk = (const float*)d_in[2];
  const float* Wv = (const float*)d_in[3];
  const float* Wo = (const float*)d_in[4];
  const float* bo = (const float*)d_in[5];
  float* out = (float*)d_out;
  char* ws = (char*)d_ws;

  unsigned short* xb  = (unsigned short*)(ws);                       // 8 MB  [4096][1024]
  unsigned short* wqt = (unsigned short*)(ws + (8ull << 20));        // 2 MB  Wq^T
  unsigned short* wkt = (unsigned short*)(ws + (10ull << 20));       // 2 MB
  unsigned short* wvt = (unsigned short*)(ws + (12ull << 20));       // 2 MB
  unsigned short* wot = (unsigned short*)(ws + (14ull << 20));       // 128 KB Wo^T
  unsigned short* q   = (unsigned short*)(ws + (15ull << 20));       // 8 MB  [b][h][t][d]
  unsigned short* k   = (unsigned short*)(ws + (23ull << 20));       // 8 MB  [b][h][t][d]
  unsigned short* vt  = (unsigned short*)(ws + (31ull << 20));       // 8 MB  [b][h][d][t]

  prep<<<7488, 256, 0, stream>>>(x, Wq, Wk, Wv, Wo, bo, xb, wqt, wkt, wvt, wot, out);
  qkv_gemm<<<dim3(32, 8, 3), 256, 0, stream>>>(xb, wqt, wkt, wvt, q, k, vt);
  attn13<<<dim3(32, 32), 256, 0, stream>>>(q, k, vt, wot, out);
}